// Round 1
// baseline (529.769 us; speedup 1.0000x reference)
//
#include <hip/hip_runtime.h>

typedef unsigned short u16;
typedef unsigned int u32;
typedef __attribute__((ext_vector_type(8))) __bf16 bf16x8;
typedef __attribute__((ext_vector_type(4))) float floatx4;
typedef __attribute__((ext_vector_type(4))) u32 uintx4;

// ---------------- helpers ----------------
__device__ __forceinline__ float bf2f(u16 u) {
  union { u32 i; float f; } v; v.i = ((u32)u) << 16; return v.f;
}
__device__ __forceinline__ u16 f2bf(float f) {
  union { float fl; u32 i; } v; v.fl = f;
  return (u16)((v.i + 0x7FFFu + ((v.i >> 16) & 1u)) >> 16);
}
__device__ __forceinline__ float lo16(u32 u) {
  union { u32 i; float f; } v; v.i = u << 16; return v.f;
}
__device__ __forceinline__ float hi16(u32 u) {
  union { u32 i; float f; } v; v.i = u & 0xffff0000u; return v.f;
}

typedef __attribute__((address_space(1))) const void* as1cv;
typedef __attribute__((address_space(3))) void* as3v;
__device__ __forceinline__ void gload16(const void* g, void* l) {
  __builtin_amdgcn_global_load_lds((as1cv)g, (as3v)l, 16, 0, 0);
}

// ---------------- ws layout (bytes) ----------------
// xp   : [32][36][36][256] bf16 (border-2 padded NHWC x)      21,233,664
// ymid : [32][34][34][256] bf16 (border-1 padded NHWC mid)    18,939,904
// offb : [32768][64] f32 (offset conv out, NHWC)               8,388,608
// wB1  : [256][2304] bf16                                      1,179,648
// wBo  : [64][2304] bf16                                         294,912
// wB3  : [256][6400] bf16                                      3,276,800
// wB2  : [256][2304] bf16                                      1,179,648
// bnp  : [6][256] f32 (s1,b1,s3,b3,s2,b2)                          6,144
static constexpr size_t OFF_XP   = 0;
static constexpr size_t OFF_YMID = 21233664;
static constexpr size_t OFF_OFFB = 40173568;
static constexpr size_t OFF_WB1  = 48562176;
static constexpr size_t OFF_WBO  = 49741824;
static constexpr size_t OFF_WB3  = 50036736;
static constexpr size_t OFF_WB2  = 53313536;
static constexpr size_t OFF_BNP  = 54493184;

// ---------------- zero fill (xp + ymid region) ----------------
__global__ __launch_bounds__(256) void zero_kernel(uintx4* __restrict__ p, int n) {
  int i = blockIdx.x * 256 + threadIdx.x;
  if (i < n) { uintx4 z = {0u, 0u, 0u, 0u}; p[i] = z; }
}

// ---------------- pack weights + bn params ----------------
__global__ __launch_bounds__(256) void prep_kernel(
    const float* __restrict__ w1, const float* __restrict__ woff,
    const float* __restrict__ w3, const float* __restrict__ w2,
    const float* __restrict__ g1, const float* __restrict__ b1,
    const float* __restrict__ m1, const float* __restrict__ v1,
    const float* __restrict__ g3, const float* __restrict__ b3,
    const float* __restrict__ m3, const float* __restrict__ v3,
    const float* __restrict__ g2, const float* __restrict__ b2,
    const float* __restrict__ m2, const float* __restrict__ v2,
    u16* __restrict__ wB1, u16* __restrict__ wBo,
    u16* __restrict__ wB3, u16* __restrict__ wB2,
    float* __restrict__ bnp)
{
  int i = blockIdx.x * 256 + threadIdx.x;
  if (i < 589824) {                    // wB1 [256][2304], k = tap*256+c
    int p = i / 2304, k = i - p * 2304;
    int tap = k >> 8, c = k & 255;
    wB1[i] = f2bf(w1[(p * 256 + c) * 9 + tap]);
    return;
  }
  i -= 589824;
  if (i < 147456) {                    // wBo [64][2304] (rows >= 50 zero)
    int p = i / 2304, k = i - p * 2304;
    int tap = k >> 8, c = k & 255;
    wBo[i] = (p < 50) ? f2bf(woff[(p * 256 + c) * 9 + tap]) : (u16)0;
    return;
  }
  i -= 147456;
  if (i < 1638400) {                   // wB3 [256][6400], k = tap*256+c (5x5)
    int p = i / 6400, k = i - p * 6400;
    int tap = k >> 8, c = k & 255;
    wB3[i] = f2bf(w3[(p * 256 + c) * 25 + tap]);
    return;
  }
  i -= 1638400;
  if (i < 589824) {                    // wB2
    int p = i / 2304, k = i - p * 2304;
    int tap = k >> 8, c = k & 255;
    wB2[i] = f2bf(w2[(p * 256 + c) * 9 + tap]);
    return;
  }
  i -= 589824;
  if (i < 1536) {                      // bn params
    int grp = i >> 8, n = i & 255;
    const float* g  = (grp < 2) ? g1 : (grp < 4) ? g3 : g2;
    const float* bb = (grp < 2) ? b1 : (grp < 4) ? b3 : b2;
    const float* mm = (grp < 2) ? m1 : (grp < 4) ? m3 : m2;
    const float* vv = (grp < 2) ? v1 : (grp < 4) ? v3 : v2;
    float sc = g[n] / sqrtf(vv[n] + 1e-5f);
    bnp[i] = (grp & 1) ? (bb[n] - mm[n] * sc) : sc;
  }
}

// ---------------- pack x: NCHW f32 -> NHWC bf16 border-2 ----------------
__global__ __launch_bounds__(256) void pack_x_kernel(const float* __restrict__ x,
                                                     u16* __restrict__ xp)
{
  __shared__ float trans[256][33];
  int b = blockIdx.x >> 5, y = blockIdx.x & 31;
  int t = threadIdx.x;
  int xi = t & 31, ch = t >> 5;
  const float* src = x + (b * 256 * 1024) + y * 32 + xi;
#pragma unroll 4
  for (int c8 = 0; c8 < 32; ++c8) {
    int c = c8 * 8 + ch;
    trans[c][xi] = src[c * 1024];
  }
  __syncthreads();
  u16* dstrow = xp + ((b * 36 + y + 2) * 36 + 2) * 256 + t;
#pragma unroll 4
  for (int xx = 0; xx < 32; ++xx)
    dstrow[xx * 256] = f2bf(trans[t][xx]);
}

// ---------------- implicit-GEMM 3x3 conv ----------------
// M = 32768 (b,y,x), N = BN*gridDim.x, K = 2304 (tap-major, c-inner)
// EPI: 0 = bn+relu -> ymid bf16 NHWC(border1); 1 = +b_off -> offb f32 [m][64];
//      2 = bn + residual(x NCHW) + relu -> out f32 NCHW
template <int BN, int WPAD, int EPI>
__global__ __launch_bounds__(256) void conv3x3_kernel(
    const u16* __restrict__ img, const u16* __restrict__ wB,
    const float* __restrict__ p0, const float* __restrict__ p1,
    const float* __restrict__ xorig, void* __restrict__ dst)
{
  constexpr int K = 2304;
  constexpr int NI = BN / 32;          // 16x16 n-tiles per wave
  constexpr int BQ = BN / 32;          // B staging instrs per wave
  constexpr int BRW = BN / 4;          // B rows per wave
  constexpr int BRD = (WPAD - 34) / 2; // extra border offset (36->1, 34->0)

  const int t = threadIdx.x;
  const int wave = t >> 6, lane = t & 63;
  const int mBlk = blockIdx.y * 128;
  const int nBlk = blockIdx.x * BN;
  const int wm = wave >> 1, wn = wave & 1;

  __shared__ u16 Alds[128 * 64];
  __shared__ u16 Blds[BN * 64];

  int arow[4];
  {
    const int r0 = wave * 32 + (lane >> 3);
#pragma unroll
    for (int q = 0; q < 4; ++q) {
      int m = mBlk + r0 + q * 8;
      int b = m >> 10, y = (m >> 5) & 31, x = m & 31;
      arow[q] = ((b * WPAD + y + BRD) * WPAD + (x + BRD)) * 256 + (lane & 7) * 8;
    }
  }
  int brow[BQ];
  {
    const int r0 = nBlk + wave * BRW + (lane >> 3);
#pragma unroll
    for (int q = 0; q < BQ; ++q)
      brow[q] = (r0 + q * 8) * K + (lane & 7) * 8;
  }

  floatx4 acc[4][NI] = {};
  u16* adst = &Alds[wave * 32 * 64];
  u16* bdst = &Blds[wave * BRW * 64];

  for (int kt = 0; kt < 36; ++kt) {
    const int tap = kt >> 2, c0 = (kt & 3) << 6;
    const int kh = tap / 3, kw = tap - kh * 3;
    const int koff = (kh * WPAD + kw) * 256 + c0;
#pragma unroll
    for (int q = 0; q < 4; ++q)
      gload16(img + (arow[q] + koff), adst + q * 512);
#pragma unroll
    for (int q = 0; q < BQ; ++q)
      gload16(wB + (brow[q] + kt * 64), bdst + q * 512);
    __syncthreads();
#pragma unroll
    for (int kk = 0; kk < 2; ++kk) {
      bf16x8 af[4], bfr[NI];
#pragma unroll
      for (int mi = 0; mi < 4; ++mi)
        af[mi] = *(const bf16x8*)&Alds[(wm * 64 + mi * 16 + (lane & 15)) * 64 + kk * 32 + ((lane >> 4) << 3)];
#pragma unroll
      for (int ni = 0; ni < NI; ++ni)
        bfr[ni] = *(const bf16x8*)&Blds[(wn * (BN / 2) + ni * 16 + (lane & 15)) * 64 + kk * 32 + ((lane >> 4) << 3)];
#pragma unroll
      for (int mi = 0; mi < 4; ++mi)
#pragma unroll
        for (int ni = 0; ni < NI; ++ni)
          acc[mi][ni] = __builtin_amdgcn_mfma_f32_16x16x32_bf16(af[mi], bfr[ni], acc[mi][ni], 0, 0, 0);
    }
    __syncthreads();
  }

#pragma unroll
  for (int ni = 0; ni < NI; ++ni) {
    const int n = nBlk + wn * (BN / 2) + ni * 16 + (lane & 15);
    float sc = 0.f, bi = 0.f;
    if constexpr (EPI == 0 || EPI == 2) { sc = p0[n]; bi = p1[n]; }
    else { sc = (n < 50) ? p0[n] : 0.f; }
#pragma unroll
    for (int mi = 0; mi < 4; ++mi) {
      const int mb = mBlk + wm * 64 + mi * 16 + ((lane >> 4) << 2);
      if constexpr (EPI == 0) {
        u16* ym = (u16*)dst;
#pragma unroll
        for (int r = 0; r < 4; ++r) {
          int m = mb + r;
          int b = m >> 10, yy = (m >> 5) & 31, xx = m & 31;
          float v = fmaxf(acc[mi][ni][r] * sc + bi, 0.f);
          ym[((b * 34 + yy + 1) * 34 + (xx + 1)) * 256 + n] = f2bf(v);
        }
      } else if constexpr (EPI == 1) {
        float* ob = (float*)dst;
#pragma unroll
        for (int r = 0; r < 4; ++r)
          ob[(mb + r) * 64 + n] = acc[mi][ni][r] + sc;
      } else {
        int b = mb >> 10, s = mb & 1023;
        const float* xr = xorig + ((b * 256 + n) << 10) + s;
        float* orow = (float*)dst + ((b * 256 + n) << 10) + s;
        floatx4 xv = *(const floatx4*)xr;
        floatx4 res;
#pragma unroll
        for (int r = 0; r < 4; ++r)
          res[r] = fmaxf(acc[mi][ni][r] * sc + bi + xv[r], 0.f);
        *(floatx4*)orow = res;
      }
    }
  }
}

// ---------------- deformable conv (fused bilinear im2col + GEMM) ----------------
// M-tile 64, N = 256 (full), K = 6400 (25 taps x 256 c)
__global__ __launch_bounds__(256) void deform_kernel(
    const u16* __restrict__ xp, const u16* __restrict__ wB,
    const float* __restrict__ offb,
    const float* __restrict__ sc3, const float* __restrict__ bi3,
    u16* __restrict__ ymid)
{
  constexpr int K = 6400;
  const int t = threadIdx.x;
  const int wave = t >> 6, lane = t & 63;
  const int mBlk = blockIdx.x * 64;

  __shared__ u16 Alds[64 * 64];
  __shared__ u16 Blds[256 * 64];

  const int srow = t >> 2, scg = t & 3;       // sampling: row 0..63, c-chunk of 16
  const int sm = mBlk + srow;
  const int sb = sm >> 10, soh = (sm >> 5) & 31, sow = sm & 31;
  const u16* ximg = xp + sb * (36 * 36 * 256);

  const int brow = (wave * 64 + (lane >> 3)) * K + (lane & 7) * 8;
  u16* bdst = &Blds[wave * 64 * 64];

  floatx4 acc[4][4] = {};

  for (int kt = 0; kt < 100; ++kt) {
    const int tap = kt >> 2, c0 = (kt & 3) << 6;
    const int ti = tap / 5, tj = tap - ti * 5;
#pragma unroll
    for (int q = 0; q < 8; ++q)
      gload16(wB + (brow + q * 8 * K + kt * 64), bdst + q * 512);
    {
      float2 ov = *(const float2*)(offb + sm * 64 + 2 * tap);
      float py = (float)(soh - 2 + ti) + ov.x;
      float px = (float)(sow - 2 + tj) + ov.y;
      // zero-outside bilinear == clamp into [-1,32] + border-2 zero-padded image
      py = fminf(32.f, fmaxf(-1.f, py));
      px = fminf(32.f, fmaxf(-1.f, px));
      float fy = floorf(py), fx = floorf(px);
      float wy1 = py - fy, wx1 = px - fx;
      float wy0 = 1.f - wy1, wx0 = 1.f - wx1;
      int ya = (int)fy + 2, xa = (int)fx + 2;
      const u16* pb = ximg + (ya * 36 + xa) * 256 + c0 + scg * 16;
      float w00 = wy0 * wx0, w01 = wy0 * wx1, w10 = wy1 * wx0, w11 = wy1 * wx1;
#pragma unroll
      for (int g = 0; g < 2; ++g) {
        uintx4 a00 = *(const uintx4*)(pb + g * 8);
        uintx4 a01 = *(const uintx4*)(pb + g * 8 + 256);
        uintx4 a10 = *(const uintx4*)(pb + g * 8 + 36 * 256);
        uintx4 a11 = *(const uintx4*)(pb + g * 8 + 36 * 256 + 256);
        uintx4 r;
#pragma unroll
        for (int e = 0; e < 4; ++e) {
          float lo = w00 * lo16(a00[e]) + w01 * lo16(a01[e]) + w10 * lo16(a10[e]) + w11 * lo16(a11[e]);
          float hi = w00 * hi16(a00[e]) + w01 * hi16(a01[e]) + w10 * hi16(a10[e]) + w11 * hi16(a11[e]);
          r[e] = ((u32)f2bf(hi) << 16) | (u32)f2bf(lo);
        }
        *(uintx4*)&Alds[srow * 64 + scg * 16 + g * 8] = r;
      }
    }
    __syncthreads();
#pragma unroll
    for (int kk = 0; kk < 2; ++kk) {
      bf16x8 af[4], bfr[4];
#pragma unroll
      for (int mi = 0; mi < 4; ++mi)
        af[mi] = *(const bf16x8*)&Alds[(mi * 16 + (lane & 15)) * 64 + kk * 32 + ((lane >> 4) << 3)];
#pragma unroll
      for (int ni = 0; ni < 4; ++ni)
        bfr[ni] = *(const bf16x8*)&Blds[(wave * 64 + ni * 16 + (lane & 15)) * 64 + kk * 32 + ((lane >> 4) << 3)];
#pragma unroll
      for (int mi = 0; mi < 4; ++mi)
#pragma unroll
        for (int ni = 0; ni < 4; ++ni)
          acc[mi][ni] = __builtin_amdgcn_mfma_f32_16x16x32_bf16(af[mi], bfr[ni], acc[mi][ni], 0, 0, 0);
    }
    __syncthreads();
  }

#pragma unroll
  for (int ni = 0; ni < 4; ++ni) {
    const int n = wave * 64 + ni * 16 + (lane & 15);
    float sc = sc3[n], bi = bi3[n];
#pragma unroll
    for (int mi = 0; mi < 4; ++mi) {
      const int mb = mBlk + mi * 16 + ((lane >> 4) << 2);
#pragma unroll
      for (int r = 0; r < 4; ++r) {
        int m = mb + r;
        int b = m >> 10, yy = (m >> 5) & 31, xx = m & 31;
        int idx = ((b * 34 + yy + 1) * 34 + (xx + 1)) * 256 + n;
        float v = fmaxf(acc[mi][ni][r] * sc + bi, 0.f) + bf2f(ymid[idx]);
        ymid[idx] = f2bf(v);
      }
    }
  }
}

// ---------------- launch ----------------
extern "C" void kernel_launch(void* const* d_in, const int* in_sizes, int n_in,
                              void* d_out, int out_size, void* d_ws, size_t ws_size,
                              hipStream_t stream)
{
  const float* x    = (const float*)d_in[0];
  const float* w1   = (const float*)d_in[1];
  const float* woff = (const float*)d_in[2];
  const float* boff = (const float*)d_in[3];
  const float* w3   = (const float*)d_in[4];
  const float* w2   = (const float*)d_in[5];
  const float* g1 = (const float*)d_in[6],  *b1 = (const float*)d_in[7];
  const float* m1 = (const float*)d_in[8],  *v1 = (const float*)d_in[9];
  const float* g3 = (const float*)d_in[10], *b3 = (const float*)d_in[11];
  const float* m3 = (const float*)d_in[12], *v3 = (const float*)d_in[13];
  const float* g2 = (const float*)d_in[14], *b2 = (const float*)d_in[15];
  const float* m2 = (const float*)d_in[16], *v2 = (const float*)d_in[17];

  char* ws = (char*)d_ws;
  u16*   xp   = (u16*)(ws + OFF_XP);
  u16*   ymid = (u16*)(ws + OFF_YMID);
  float* offb = (float*)(ws + OFF_OFFB);
  u16*   wB1  = (u16*)(ws + OFF_WB1);
  u16*   wBo  = (u16*)(ws + OFF_WBO);
  u16*   wB3  = (u16*)(ws + OFF_WB3);
  u16*   wB2  = (u16*)(ws + OFF_WB2);
  float* bnp  = (float*)(ws + OFF_BNP);

  // zero xp + ymid (adjacent, 40,173,568 B = 2,510,848 x 16 B)
  zero_kernel<<<9808, 256, 0, stream>>>((uintx4*)ws, 2510848);
  // pack weights + bn params (2,967,040 elems = 11590 * 256)
  prep_kernel<<<11590, 256, 0, stream>>>(w1, woff, w3, w2,
                                         g1, b1, m1, v1, g3, b3, m3, v3,
                                         g2, b2, m2, v2,
                                         wB1, wBo, wB3, wB2, bnp);
  // pack x to NHWC bf16 border-2
  pack_x_kernel<<<1024, 256, 0, stream>>>(x, xp);
  // offset conv (N=64 padded, +b_off) -> offb
  conv3x3_kernel<64, 36, 1><<<dim3(1, 256), 256, 0, stream>>>(
      xp, wBo, boff, nullptr, nullptr, (void*)offb);
  // conv1 + bn1 + relu -> ymid
  conv3x3_kernel<128, 36, 0><<<dim3(2, 256), 256, 0, stream>>>(
      xp, wB1, bnp + 0, bnp + 256, nullptr, (void*)ymid);
  // deform conv + bn3 + relu, accumulate into ymid
  deform_kernel<<<512, 256, 0, stream>>>(xp, wB3, offb, bnp + 512, bnp + 768, ymid);
  // conv2 + bn2 + residual + relu -> out (f32 NCHW)
  conv3x3_kernel<128, 34, 2><<<dim3(2, 256), 256, 0, stream>>>(
      ymid, wB2, bnp + 1024, bnp + 1280, x, d_out);
}

// Round 2
// 503.041 us; speedup vs baseline: 1.0531x; 1.0531x over previous
//
#include <hip/hip_runtime.h>

typedef unsigned short u16;
typedef unsigned int u32;
typedef __attribute__((ext_vector_type(8))) _Float16 half8;
typedef __attribute__((ext_vector_type(4))) float floatx4;
typedef __attribute__((ext_vector_type(4))) u32 uintx4;

// ---------------- helpers ----------------
__device__ __forceinline__ u16 f2h(float f) {
  union { _Float16 h; u16 u; } v; v.h = (_Float16)f; return v.u;
}
__device__ __forceinline__ float h2f(u16 u) {
  union { u16 u; _Float16 h; } v; v.u = u; return (float)v.h;
}

typedef __attribute__((address_space(1))) const void* as1cv;
typedef __attribute__((address_space(3))) void* as3v;
__device__ __forceinline__ void gload16(const void* g, void* l) {
  __builtin_amdgcn_global_load_lds((as1cv)g, (as3v)l, 16, 0, 0);
}

// ---------------- ws layout (bytes) ----------------
// xp   : [32][36][36][256] f16 (border-2 padded NHWC x)       21,233,664
// ymid : [32][34][34][256] f16 (border-1 padded NHWC mid)     18,939,904
// offb : [32768][64] f32 (offset conv out, NHWC)               8,388,608
// wB1  : [256][2304] f16                                       1,179,648
// wBo  : [64][2304] f16                                          294,912
// wB3  : [256][6400] f16                                       3,276,800
// wB2  : [256][2304] f16                                       1,179,648
// bnp  : [6][256] f32 (s1,b1,s3,b3,s2,b2)                          6,144
static constexpr size_t OFF_XP   = 0;
static constexpr size_t OFF_YMID = 21233664;
static constexpr size_t OFF_OFFB = 40173568;
static constexpr size_t OFF_WB1  = 48562176;
static constexpr size_t OFF_WBO  = 49741824;
static constexpr size_t OFF_WB3  = 50036736;
static constexpr size_t OFF_WB2  = 53313536;
static constexpr size_t OFF_BNP  = 54493184;

// ---------------- zero fill (xp + ymid region) ----------------
__global__ __launch_bounds__(256) void zero_kernel(uintx4* __restrict__ p, int n) {
  int i = blockIdx.x * 256 + threadIdx.x;
  if (i < n) { uintx4 z = {0u, 0u, 0u, 0u}; p[i] = z; }
}

// ---------------- pack weights + bn params ----------------
__global__ __launch_bounds__(256) void prep_kernel(
    const float* __restrict__ w1, const float* __restrict__ woff,
    const float* __restrict__ w3, const float* __restrict__ w2,
    const float* __restrict__ g1, const float* __restrict__ b1,
    const float* __restrict__ m1, const float* __restrict__ v1,
    const float* __restrict__ g3, const float* __restrict__ b3,
    const float* __restrict__ m3, const float* __restrict__ v3,
    const float* __restrict__ g2, const float* __restrict__ b2,
    const float* __restrict__ m2, const float* __restrict__ v2,
    u16* __restrict__ wB1, u16* __restrict__ wBo,
    u16* __restrict__ wB3, u16* __restrict__ wB2,
    float* __restrict__ bnp)
{
  int i = blockIdx.x * 256 + threadIdx.x;
  if (i < 589824) {                    // wB1 [256][2304], k = tap*256+c
    int p = i / 2304, k = i - p * 2304;
    int tap = k >> 8, c = k & 255;
    wB1[i] = f2h(w1[(p * 256 + c) * 9 + tap]);
    return;
  }
  i -= 589824;
  if (i < 147456) {                    // wBo [64][2304] (rows >= 50 zero)
    int p = i / 2304, k = i - p * 2304;
    int tap = k >> 8, c = k & 255;
    wBo[i] = (p < 50) ? f2h(woff[(p * 256 + c) * 9 + tap]) : (u16)0;
    return;
  }
  i -= 147456;
  if (i < 1638400) {                   // wB3 [256][6400], k = tap*256+c (5x5)
    int p = i / 6400, k = i - p * 6400;
    int tap = k >> 8, c = k & 255;
    wB3[i] = f2h(w3[(p * 256 + c) * 25 + tap]);
    return;
  }
  i -= 1638400;
  if (i < 589824) {                    // wB2
    int p = i / 2304, k = i - p * 2304;
    int tap = k >> 8, c = k & 255;
    wB2[i] = f2h(w2[(p * 256 + c) * 9 + tap]);
    return;
  }
  i -= 589824;
  if (i < 1536) {                      // bn params
    int grp = i >> 8, n = i & 255;
    const float* g  = (grp < 2) ? g1 : (grp < 4) ? g3 : g2;
    const float* bb = (grp < 2) ? b1 : (grp < 4) ? b3 : b2;
    const float* mm = (grp < 2) ? m1 : (grp < 4) ? m3 : m2;
    const float* vv = (grp < 2) ? v1 : (grp < 4) ? v3 : v2;
    float sc = g[n] / sqrtf(vv[n] + 1e-5f);
    bnp[i] = (grp & 1) ? (bb[n] - mm[n] * sc) : sc;
  }
}

// ---------------- pack x: NCHW f32 -> NHWC f16 border-2 ----------------
__global__ __launch_bounds__(256) void pack_x_kernel(const float* __restrict__ x,
                                                     u16* __restrict__ xp)
{
  __shared__ float trans[256][33];
  int b = blockIdx.x >> 5, y = blockIdx.x & 31;
  int t = threadIdx.x;
  int xi = t & 31, ch = t >> 5;
  const float* src = x + (b * 256 * 1024) + y * 32 + xi;
#pragma unroll 4
  for (int c8 = 0; c8 < 32; ++c8) {
    int c = c8 * 8 + ch;
    trans[c][xi] = src[c * 1024];
  }
  __syncthreads();
  u16* dstrow = xp + ((b * 36 + y + 2) * 36 + 2) * 256 + t;
#pragma unroll 4
  for (int xx = 0; xx < 32; ++xx)
    dstrow[xx * 256] = f2h(trans[t][xx]);
}

// ---------------- implicit-GEMM 3x3 conv ----------------
// M = 32768 (b,y,x), N = BN*gridDim.x, K = 2304 (tap-major, c-inner)
// EPI: 0 = bn+relu -> ymid f16 NHWC(border1); 1 = +b_off -> offb f32 [m][64];
//      2 = bn + residual(x NCHW) + relu -> out f32 NCHW
template <int BN, int WPAD, int EPI>
__global__ __launch_bounds__(256) void conv3x3_kernel(
    const u16* __restrict__ img, const u16* __restrict__ wB,
    const float* __restrict__ p0, const float* __restrict__ p1,
    const float* __restrict__ xorig, void* __restrict__ dst)
{
  constexpr int K = 2304;
  constexpr int NI = BN / 32;          // 16x16 n-tiles per wave
  constexpr int BQ = BN / 32;          // B staging instrs per wave
  constexpr int BRW = BN / 4;          // B rows per wave
  constexpr int BRD = (WPAD - 34) / 2; // extra border offset (36->1, 34->0)

  const int t = threadIdx.x;
  const int wave = t >> 6, lane = t & 63;
  const int mBlk = blockIdx.y * 128;
  const int nBlk = blockIdx.x * BN;
  const int wm = wave >> 1, wn = wave & 1;

  __shared__ u16 Alds[128 * 64];
  __shared__ u16 Blds[BN * 64];

  int arow[4];
  {
    const int r0 = wave * 32 + (lane >> 3);
#pragma unroll
    for (int q = 0; q < 4; ++q) {
      int m = mBlk + r0 + q * 8;
      int b = m >> 10, y = (m >> 5) & 31, x = m & 31;
      arow[q] = ((b * WPAD + y + BRD) * WPAD + (x + BRD)) * 256 + (lane & 7) * 8;
    }
  }
  int brow[BQ];
  {
    const int r0 = nBlk + wave * BRW + (lane >> 3);
#pragma unroll
    for (int q = 0; q < BQ; ++q)
      brow[q] = (r0 + q * 8) * K + (lane & 7) * 8;
  }

  floatx4 acc[4][NI] = {};
  u16* adst = &Alds[wave * 32 * 64];
  u16* bdst = &Blds[wave * BRW * 64];

  for (int kt = 0; kt < 36; ++kt) {
    const int tap = kt >> 2, c0 = (kt & 3) << 6;
    const int kh = tap / 3, kw = tap - kh * 3;
    const int koff = (kh * WPAD + kw) * 256 + c0;
#pragma unroll
    for (int q = 0; q < 4; ++q)
      gload16(img + (arow[q] + koff), adst + q * 512);
#pragma unroll
    for (int q = 0; q < BQ; ++q)
      gload16(wB + (brow[q] + kt * 64), bdst + q * 512);
    __syncthreads();
#pragma unroll
    for (int kk = 0; kk < 2; ++kk) {
      half8 af[4], bfr[NI];
#pragma unroll
      for (int mi = 0; mi < 4; ++mi)
        af[mi] = *(const half8*)&Alds[(wm * 64 + mi * 16 + (lane & 15)) * 64 + kk * 32 + ((lane >> 4) << 3)];
#pragma unroll
      for (int ni = 0; ni < NI; ++ni)
        bfr[ni] = *(const half8*)&Blds[(wn * (BN / 2) + ni * 16 + (lane & 15)) * 64 + kk * 32 + ((lane >> 4) << 3)];
#pragma unroll
      for (int mi = 0; mi < 4; ++mi)
#pragma unroll
        for (int ni = 0; ni < NI; ++ni)
          acc[mi][ni] = __builtin_amdgcn_mfma_f32_16x16x32_f16(af[mi], bfr[ni], acc[mi][ni], 0, 0, 0);
    }
    __syncthreads();
  }

#pragma unroll
  for (int ni = 0; ni < NI; ++ni) {
    const int n = nBlk + wn * (BN / 2) + ni * 16 + (lane & 15);
    float sc = 0.f, bi = 0.f;
    if constexpr (EPI == 0 || EPI == 2) { sc = p0[n]; bi = p1[n]; }
    else { sc = (n < 50) ? p0[n] : 0.f; }
#pragma unroll
    for (int mi = 0; mi < 4; ++mi) {
      const int mb = mBlk + wm * 64 + mi * 16 + ((lane >> 4) << 2);
      if constexpr (EPI == 0) {
        u16* ym = (u16*)dst;
#pragma unroll
        for (int r = 0; r < 4; ++r) {
          int m = mb + r;
          int b = m >> 10, yy = (m >> 5) & 31, xx = m & 31;
          float v = fmaxf(acc[mi][ni][r] * sc + bi, 0.f);
          ym[((b * 34 + yy + 1) * 34 + (xx + 1)) * 256 + n] = f2h(v);
        }
      } else if constexpr (EPI == 1) {
        float* ob = (float*)dst;
#pragma unroll
        for (int r = 0; r < 4; ++r)
          ob[(mb + r) * 64 + n] = acc[mi][ni][r] + sc;
      } else {
        int b = mb >> 10, s = mb & 1023;
        const float* xr = xorig + ((b * 256 + n) << 10) + s;
        float* orow = (float*)dst + ((b * 256 + n) << 10) + s;
        floatx4 xv = *(const floatx4*)xr;
        floatx4 res;
#pragma unroll
        for (int r = 0; r < 4; ++r)
          res[r] = fmaxf(acc[mi][ni][r] * sc + bi + xv[r], 0.f);
        *(floatx4*)orow = res;
      }
    }
  }
}

// ---------------- deformable conv (fused bilinear im2col + GEMM) ----------------
// M-tile 64, N = 256 (full), K = 6400 (25 taps x 256 c)
// Loop: tap outer (coords/weights hoisted), 64-ch chunk inner.
// Blend in packed f16 (v_pk_fma_f16) on half8 vectors.
__global__ __launch_bounds__(256) void deform_kernel(
    const u16* __restrict__ xp, const u16* __restrict__ wB,
    const float* __restrict__ offb,
    const float* __restrict__ sc3, const float* __restrict__ bi3,
    u16* __restrict__ ymid)
{
  constexpr int K = 6400;
  const int t = threadIdx.x;
  const int wave = t >> 6, lane = t & 63;
  const int mBlk = blockIdx.x * 64;

  __shared__ u16 Alds[64 * 64];
  __shared__ u16 Blds[256 * 64];

  const int srow = t >> 2, scg = t & 3;       // sampling: row 0..63, c-chunk of 16
  const int sm = mBlk + srow;
  const int sb = sm >> 10, soh = (sm >> 5) & 31, sow = sm & 31;
  const u16* ximg = xp + sb * (36 * 36 * 256) + scg * 16;
  const float2* offrow = (const float2*)(offb + sm * 64);

  const int brow = (wave * 64 + (lane >> 3)) * K + (lane & 7) * 8;
  u16* bdst = &Blds[wave * 64 * 64];

  floatx4 acc[4][4] = {};

  for (int tap = 0; tap < 25; ++tap) {
    const int ti = tap / 5, tj = tap - ti * 5;
    float2 ov = offrow[tap];
    float py = (float)(soh - 2 + ti) + ov.x;
    float px = (float)(sow - 2 + tj) + ov.y;
    // zero-outside bilinear == clamp into [-1,32] + border-2 zero-padded image
    py = fminf(32.f, fmaxf(-1.f, py));
    px = fminf(32.f, fmaxf(-1.f, px));
    float fy = floorf(py), fx = floorf(px);
    float wy1 = py - fy, wx1 = px - fx;
    float wy0 = 1.f - wy1, wx0 = 1.f - wx1;
    int ya = (int)fy + 2, xa = (int)fx + 2;
    const u16* pb0 = ximg + (ya * 36 + xa) * 256;
    _Float16 hw00 = (_Float16)(wy0 * wx0), hw01 = (_Float16)(wy0 * wx1);
    _Float16 hw10 = (_Float16)(wy1 * wx0), hw11 = (_Float16)(wy1 * wx1);

#pragma unroll
    for (int cc = 0; cc < 4; ++cc) {
      const int kt = tap * 4 + cc;
#pragma unroll
      for (int q = 0; q < 8; ++q)
        gload16(wB + (brow + q * 8 * K + kt * 64), bdst + q * 512);
      const u16* pb = pb0 + cc * 64;
#pragma unroll
      for (int g = 0; g < 2; ++g) {
        half8 a00 = *(const half8*)(pb + g * 8);
        half8 a01 = *(const half8*)(pb + g * 8 + 256);
        half8 a10 = *(const half8*)(pb + g * 8 + 36 * 256);
        half8 a11 = *(const half8*)(pb + g * 8 + 36 * 256 + 256);
        half8 r = a00 * hw00 + a01 * hw01 + a10 * hw10 + a11 * hw11;
        *(half8*)&Alds[srow * 64 + scg * 16 + g * 8] = r;
      }
      __syncthreads();
#pragma unroll
      for (int kk = 0; kk < 2; ++kk) {
        half8 af[4], bfr[4];
#pragma unroll
        for (int mi = 0; mi < 4; ++mi)
          af[mi] = *(const half8*)&Alds[(mi * 16 + (lane & 15)) * 64 + kk * 32 + ((lane >> 4) << 3)];
#pragma unroll
        for (int ni = 0; ni < 4; ++ni)
          bfr[ni] = *(const half8*)&Blds[(wave * 64 + ni * 16 + (lane & 15)) * 64 + kk * 32 + ((lane >> 4) << 3)];
#pragma unroll
        for (int mi = 0; mi < 4; ++mi)
#pragma unroll
          for (int ni = 0; ni < 4; ++ni)
            acc[mi][ni] = __builtin_amdgcn_mfma_f32_16x16x32_f16(af[mi], bfr[ni], acc[mi][ni], 0, 0, 0);
      }
      __syncthreads();
    }
  }

#pragma unroll
  for (int ni = 0; ni < 4; ++ni) {
    const int n = wave * 64 + ni * 16 + (lane & 15);
    float sc = sc3[n], bi = bi3[n];
#pragma unroll
    for (int mi = 0; mi < 4; ++mi) {
      const int mb = mBlk + mi * 16 + ((lane >> 4) << 2);
#pragma unroll
      for (int r = 0; r < 4; ++r) {
        int m = mb + r;
        int b = m >> 10, yy = (m >> 5) & 31, xx = m & 31;
        int idx = ((b * 34 + yy + 1) * 34 + (xx + 1)) * 256 + n;
        float v = fmaxf(acc[mi][ni][r] * sc + bi, 0.f) + h2f(ymid[idx]);
        ymid[idx] = f2h(v);
      }
    }
  }
}

// ---------------- launch ----------------
extern "C" void kernel_launch(void* const* d_in, const int* in_sizes, int n_in,
                              void* d_out, int out_size, void* d_ws, size_t ws_size,
                              hipStream_t stream)
{
  const float* x    = (const float*)d_in[0];
  const float* w1   = (const float*)d_in[1];
  const float* woff = (const float*)d_in[2];
  const float* boff = (const float*)d_in[3];
  const float* w3   = (const float*)d_in[4];
  const float* w2   = (const float*)d_in[5];
  const float* g1 = (const float*)d_in[6],  *b1 = (const float*)d_in[7];
  const float* m1 = (const float*)d_in[8],  *v1 = (const float*)d_in[9];
  const float* g3 = (const float*)d_in[10], *b3 = (const float*)d_in[11];
  const float* m3 = (const float*)d_in[12], *v3 = (const float*)d_in[13];
  const float* g2 = (const float*)d_in[14], *b2 = (const float*)d_in[15];
  const float* m2 = (const float*)d_in[16], *v2 = (const float*)d_in[17];

  char* ws = (char*)d_ws;
  u16*   xp   = (u16*)(ws + OFF_XP);
  u16*   ymid = (u16*)(ws + OFF_YMID);
  float* offb = (float*)(ws + OFF_OFFB);
  u16*   wB1  = (u16*)(ws + OFF_WB1);
  u16*   wBo  = (u16*)(ws + OFF_WBO);
  u16*   wB3  = (u16*)(ws + OFF_WB3);
  u16*   wB2  = (u16*)(ws + OFF_WB2);
  float* bnp  = (float*)(ws + OFF_BNP);

  // zero xp + ymid (adjacent, 40,173,568 B = 2,510,848 x 16 B)
  zero_kernel<<<9808, 256, 0, stream>>>((uintx4*)ws, 2510848);
  // pack weights + bn params (2,967,040 elems = 11590 * 256)
  prep_kernel<<<11590, 256, 0, stream>>>(w1, woff, w3, w2,
                                         g1, b1, m1, v1, g3, b3, m3, v3,
                                         g2, b2, m2, v2,
                                         wB1, wBo, wB3, wB2, bnp);
  // pack x to NHWC f16 border-2
  pack_x_kernel<<<1024, 256, 0, stream>>>(x, xp);
  // offset conv (N=64 padded, +b_off) -> offb
  conv3x3_kernel<64, 36, 1><<<dim3(1, 256), 256, 0, stream>>>(
      xp, wBo, boff, nullptr, nullptr, (void*)offb);
  // conv1 + bn1 + relu -> ymid
  conv3x3_kernel<128, 36, 0><<<dim3(2, 256), 256, 0, stream>>>(
      xp, wB1, bnp + 0, bnp + 256, nullptr, (void*)ymid);
  // deform conv + bn3 + relu, accumulate into ymid
  deform_kernel<<<512, 256, 0, stream>>>(xp, wB3, offb, bnp + 512, bnp + 768, ymid);
  // conv2 + bn2 + residual + relu -> out (f32 NCHW)
  conv3x3_kernel<128, 34, 2><<<dim3(2, 256), 256, 0, stream>>>(
      ymid, wB2, bnp + 1024, bnp + 1280, x, d_out);
}